// Round 2
// baseline (700.073 us; speedup 1.0000x reference)
//
#include <hip/hip_runtime.h>
#include <hip/hip_bf16.h>
#include <stdint.h>

#define EMB   2048
#define NH    16
#define HD    128
#define BATCH 4
#define SEQ   2048

typedef __bf16 bf16_t;
typedef __bf16 bf16x8 __attribute__((ext_vector_type(8)));
typedef __bf16 bf16x4 __attribute__((ext_vector_type(4)));
typedef float  f32x4  __attribute__((ext_vector_type(4)));
typedef float  f32x16 __attribute__((ext_vector_type(16)));

__device__ inline void gload_lds16(const void* g, void* l) {
  __builtin_amdgcn_global_load_lds(
      (const __attribute__((address_space(1))) uint32_t*)g,
      (__attribute__((address_space(3))) uint32_t*)l, 16, 0, 0);
}

__device__ inline uint32_t pack_bf2(float a, float b) {
  uint16_t lo = __builtin_bit_cast(uint16_t, (bf16_t)a);
  uint16_t hi = __builtin_bit_cast(uint16_t, (bf16_t)b);
  return (uint32_t)lo | ((uint32_t)hi << 16);
}

// ---------------- input conversion kernels ----------------

__global__ __launch_bounds__(256) void conv_bf16(const float* __restrict__ x,
                                                 bf16_t* __restrict__ y) {
  size_t t = (size_t)blockIdx.x * 256 + threadIdx.x;
  float4 v = ((const float4*)x)[t];
  bf16x4 o;
  o[0] = (bf16_t)v.x; o[1] = (bf16_t)v.y; o[2] = (bf16_t)v.z; o[3] = (bf16_t)v.w;
  ((bf16x4*)y)[t] = o;
}

// W[k][n] f32 -> Wt[n][k] bf16 (LDS 32x32 tile transpose)
__global__ __launch_bounds__(256) void convT_w(const float* __restrict__ W,
                                               bf16_t* __restrict__ Wt) {
  __shared__ float t[32][33];
  int tx = threadIdx.x & 31, ty = threadIdx.x >> 5;
  int nb = blockIdx.x * 32, kb = blockIdx.y * 32;
#pragma unroll
  for (int i = 0; i < 4; ++i)
    t[ty + 8 * i][tx] = W[(size_t)(kb + ty + 8 * i) * EMB + nb + tx];
  __syncthreads();
#pragma unroll
  for (int i = 0; i < 4; ++i)
    Wt[(size_t)(nb + ty + 8 * i) * EMB + kb + tx] = (bf16_t)t[tx][ty + 8 * i];
}

// mask int32 [S][S] -> bitmask [S][S/32]
__global__ __launch_bounds__(256) void pack_mask(const int* __restrict__ mask,
                                                 uint32_t* __restrict__ maskb) {
  int t = blockIdx.x * 256 + threadIdx.x;   // t < 2048*64
  int q = t >> 6, w = t & 63;
  const int* row = mask + (size_t)q * SEQ + w * 32;
  uint32_t acc = 0;
#pragma unroll 8
  for (int i = 0; i < 32; ++i) acc |= (row[i] != 0 ? 1u : 0u) << i;
  maskb[t] = acc;
}

// ---------------- 128x128 bf16 GEMM (m97 structure) ----------------
// C[M=8192][N=2048] = A[M][K=2048] * Wt[N][K]^T
// MODE 0: out bf16 [B][H][S][D]   (Q,K)
// MODE 1: out bf16 [B][H][D][S]   (V transposed)
// MODE 2: out f32 [M][N] + bias[n]
template <int MODE>
__global__ __launch_bounds__(256) void gemm128(const bf16_t* __restrict__ A,
                                               const bf16_t* __restrict__ Bt,
                                               bf16_t* __restrict__ outb,
                                               float* __restrict__ outf,
                                               const float* __restrict__ bias) {
  __shared__ bf16_t As[128 * 32];
  __shared__ bf16_t Bs[128 * 32];
  const int tid = threadIdx.x;
  const int wid = tid >> 6, lane = tid & 63;
  const int wr = wid >> 1, wc = wid & 1;
  const int m0 = blockIdx.y * 128, n0 = blockIdx.x * 128;

  f32x4 acc[4][4] = {};

  const int sr = lane >> 2;          // row within 16-row staging group
  const int sc = (lane & 3) * 8;     // k element offset (16B chunk)
  const int ia0 = wid * 2;

  for (int kt = 0; kt < EMB / 32; ++kt) {
    const int k0 = kt * 32;
#pragma unroll
    for (int j = 0; j < 2; ++j) {
      int i = ia0 + j;
      int r = i * 16 + sr;
      gload_lds16(&A[(size_t)(m0 + r) * EMB + k0 + sc], &As[i * 512]);
      gload_lds16(&Bt[(size_t)(n0 + r) * EMB + k0 + sc], &Bs[i * 512]);
    }
    asm volatile("s_waitcnt vmcnt(0)" ::: "memory");
    __syncthreads();

    const int fr = lane & 15;
    const int fk = (lane >> 4) * 8;
    bf16x8 af[4], bfr[4];
#pragma unroll
    for (int mf = 0; mf < 4; ++mf)
      af[mf] = *(const bf16x8*)&As[(wr * 64 + mf * 16 + fr) * 32 + fk];
#pragma unroll
    for (int nf = 0; nf < 4; ++nf)
      bfr[nf] = *(const bf16x8*)&Bs[(wc * 64 + nf * 16 + fr) * 32 + fk];
#pragma unroll
    for (int mf = 0; mf < 4; ++mf)
#pragma unroll
      for (int nf = 0; nf < 4; ++nf)
        acc[mf][nf] = __builtin_amdgcn_mfma_f32_16x16x32_bf16(af[mf], bfr[nf],
                                                              acc[mf][nf], 0, 0, 0);
    __syncthreads();
  }

  // epilogue.  D layout (16x16): col = lane&15, row = (lane>>4)*4 + r
  const int col0 = lane & 15;
  const int row0 = (lane >> 4) * 4;
#pragma unroll
  for (int mf = 0; mf < 4; ++mf) {
#pragma unroll
    for (int r = 0; r < 4; ++r) {
      int m = m0 + wr * 64 + mf * 16 + row0 + r;
#pragma unroll
      for (int nf = 0; nf < 4; ++nf) {
        int n = n0 + wc * 64 + nf * 16 + col0;
        float v = acc[mf][nf][r];
        if (MODE == 0) {
          int b = m >> 11, s = m & 2047, h = n >> 7, d = n & 127;
          outb[((size_t)(b * NH + h) * SEQ + s) * HD + d] = (bf16_t)v;
        } else if (MODE == 1) {
          int b = m >> 11, s = m & 2047, h = n >> 7, d = n & 127;
          outb[((size_t)(b * NH + h) * HD + d) * SEQ + s] = (bf16_t)v;
        } else {
          outf[(size_t)m * EMB + n] = v + bias[n];
        }
      }
    }
  }
}

// ---------------- fused masked flash attention ----------------
// Q,K: [B][H][S][D] bf16; Vt: [B][H][D][S] bf16; O: [B][S][E] bf16 (merged heads)
// 4 waves/block, 32 q-rows/wave, KV tile = 64. Swapped-operand MFMA:
//  S^T = mfma(K, Q)  -> per-lane column of scores (lane-local softmax)
//  O^T = mfma(Vt, P^T) -> per-lane output column
// NOTE: lane l and lane l^32 share the same q but each holds only HALF the
// s_local values (row = (r&3)+8*(r>>2)+4*hi) -> max/sum MUST pair-reduce
// across the ^32 partner before exponentiation / normalization.
__global__ __launch_bounds__(256, 2) void attn_fwd(const bf16_t* __restrict__ Q,
                                                   const bf16_t* __restrict__ K,
                                                   const bf16_t* __restrict__ Vt,
                                                   const uint32_t* __restrict__ maskb,
                                                   bf16_t* __restrict__ O) {
  __shared__ bf16_t Ks[64 * 128];   // [s][d], 16B-chunk XOR swizzle by (s&7)
  __shared__ bf16_t Vs[128 * 64];   // [d][j], 16B-chunk XOR swizzle by (d&7)
  const int tid = threadIdx.x;
  const int wid = tid >> 6, lane = tid & 63;
  const int ln = lane & 31, hi = lane >> 5;
  const int bh = blockIdx.y;
  const int b = bh >> 4, h = bh & 15;
  const int q = blockIdx.x * 128 + wid * 32 + ln;   // this lane's query row
  const float SCALE = 0.08838834764831845f;         // 1/sqrt(128)

  // Q fragments in registers (B-operand of swapped QK^T)
  bf16x8 qf[8];
  const bf16_t* qrow = Q + ((size_t)bh * SEQ + q) * HD;
#pragma unroll
  for (int ks = 0; ks < 8; ++ks)
    qf[ks] = *(const bf16x8*)&qrow[ks * 16 + hi * 8];

  f32x16 oacc[4] = {};
  float m_run = -1e30f, l_run = 0.f;

  for (int kt = 0; kt < SEQ / 64; ++kt) {
    const int k0 = kt * 64;
#pragma unroll
    for (int j = 0; j < 4; ++j) {
      int i = wid * 4 + j;
      {  // K tile: 4 rows (256B each) per inst
        int r = i * 4 + (lane >> 4);
        int c = lane & 15;
        gload_lds16(&K[((size_t)bh * SEQ + k0 + r) * HD + ((c ^ (r & 7)) * 8)],
                    &Ks[i * 512]);
      }
      {  // V tile: 8 rows (128B each) per inst
        int r = i * 8 + (lane >> 3);
        int c = lane & 7;
        gload_lds16(&Vt[((size_t)bh * HD + r) * SEQ + k0 + ((c ^ (r & 7)) * 8)],
                    &Vs[i * 512]);
      }
    }
    asm volatile("s_waitcnt vmcnt(0)" ::: "memory");
    __syncthreads();

    // S^T[s_local][q] : 64 x 32 per wave, 2 M-frags
    f32x16 sacc[2] = {};
#pragma unroll
    for (int ks = 0; ks < 8; ++ks) {
#pragma unroll
      for (int mf = 0; mf < 2; ++mf) {
        int row = mf * 32 + ln;
        bf16x8 kf = *(const bf16x8*)&Ks[row * 128 + (((2 * ks + hi) ^ (row & 7)) * 8)];
        sacc[mf] = __builtin_amdgcn_mfma_f32_32x32x16_bf16(kf, qf[ks], sacc[mf], 0, 0, 0);
      }
    }

    // mask + online softmax.  Lane owns 32 of the 64 s-values for its q;
    // partner lane (^32) owns the other 32 -> pair-reduce max and sum.
    const uint2 mw = *(const uint2*)&maskb[(size_t)q * 64 + (k0 >> 5)];
    float s0[16], s1[16];
    float pmax = -1e30f;
#pragma unroll
    for (int r = 0; r < 16; ++r) {
      const int bit = (r & 3) + 8 * (r >> 2) + 4 * hi;   // s_local within 32-block
      float va = ((mw.x >> bit) & 1) ? sacc[0][r] * SCALE : -1e20f;
      float vb = ((mw.y >> bit) & 1) ? sacc[1][r] * SCALE : -1e20f;
      s0[r] = va; s1[r] = vb;
      pmax = fmaxf(pmax, fmaxf(va, vb));
    }
    pmax = fmaxf(pmax, __shfl_xor(pmax, 32, 64));        // pair-reduce max
    const float mnew = fmaxf(m_run, pmax);
    const float corr = __expf(m_run - mnew);
    float psum = 0.f;
    uint32_t pk[2][4][2];
#pragma unroll
    for (int g = 0; g < 4; ++g) {
      float p0 = __expf(s0[4 * g + 0] - mnew);
      float p1 = __expf(s0[4 * g + 1] - mnew);
      float p2 = __expf(s0[4 * g + 2] - mnew);
      float p3 = __expf(s0[4 * g + 3] - mnew);
      psum += (p0 + p1) + (p2 + p3);
      pk[0][g][0] = pack_bf2(p0, p1);
      pk[0][g][1] = pack_bf2(p2, p3);
      float q0 = __expf(s1[4 * g + 0] - mnew);
      float q1 = __expf(s1[4 * g + 1] - mnew);
      float q2 = __expf(s1[4 * g + 2] - mnew);
      float q3 = __expf(s1[4 * g + 3] - mnew);
      psum += (q0 + q1) + (q2 + q3);
      pk[1][g][0] = pack_bf2(q0, q1);
      pk[1][g][1] = pack_bf2(q2, q3);
    }
    psum += __shfl_xor(psum, 32, 64);                    // pair-reduce sum
    m_run = mnew;
    l_run = l_run * corr + psum;
#pragma unroll
    for (int mv = 0; mv < 4; ++mv)
#pragma unroll
      for (int r = 0; r < 16; ++r) oacc[mv][r] *= corr;

    // exchange halves: partner lane (^32) has the other 4-row j-groups (same q)
    uint32_t sw[2][4][2];
#pragma unroll
    for (int mf = 0; mf < 2; ++mf)
#pragma unroll
      for (int g = 0; g < 4; ++g)
#pragma unroll
        for (int u = 0; u < 2; ++u)
          sw[mf][g][u] = (uint32_t)__shfl_xor((int)pk[mf][g][u], 32, 64);

    // O^T[d][q] += Vt[d][j] * P^T[j][q]
#pragma unroll
    for (int ks = 0; ks < 4; ++ks) {
      const int mfp = ks >> 1;
      const int gA = (2 * ks) & 3;
      const int gB = (2 * ks + 1) & 3;
      uint32_t b0 = hi ? sw[mfp][gB][0] : pk[mfp][gA][0];
      uint32_t b1 = hi ? sw[mfp][gB][1] : pk[mfp][gA][1];
      uint32_t b2 = hi ? pk[mfp][gB][0] : sw[mfp][gA][0];
      uint32_t b3 = hi ? pk[mfp][gB][1] : sw[mfp][gA][1];
      uint4 bw = make_uint4(b0, b1, b2, b3);
      bf16x8 pb = __builtin_bit_cast(bf16x8, bw);
#pragma unroll
      for (int mv = 0; mv < 4; ++mv) {
        int row = mv * 32 + ln;
        bf16x8 vf = *(const bf16x8*)&Vs[row * 64 + (((2 * ks + hi) ^ (row & 7)) * 8)];
        oacc[mv] = __builtin_amdgcn_mfma_f32_32x32x16_bf16(vf, pb, oacc[mv], 0, 0, 0);
      }
    }
    __syncthreads();
  }

  // epilogue: O[b][q][h*128+d] = oacc/l ; D rows d = (r&3)+8*(r>>2)+4*hi (+32*mv)
  const float invl = 1.f / l_run;
  bf16_t* orow = O + ((size_t)b * SEQ + q) * EMB + h * HD;
#pragma unroll
  for (int mv = 0; mv < 4; ++mv) {
#pragma unroll
    for (int g = 0; g < 4; ++g) {
      int d = mv * 32 + 8 * g + 4 * hi;
      bf16x4 ov;
      ov[0] = (bf16_t)(oacc[mv][4 * g + 0] * invl);
      ov[1] = (bf16_t)(oacc[mv][4 * g + 1] * invl);
      ov[2] = (bf16_t)(oacc[mv][4 * g + 2] * invl);
      ov[3] = (bf16_t)(oacc[mv][4 * g + 3] * invl);
      *(bf16x4*)&orow[d] = ov;
    }
  }
}

// ---------------- host launch ----------------

extern "C" void kernel_launch(void* const* d_in, const int* in_sizes, int n_in,
                              void* d_out, int out_size, void* d_ws, size_t ws_size,
                              hipStream_t stream) {
  const float* values = (const float*)d_in[0];
  const float* keys   = (const float*)d_in[1];
  const float* query  = (const float*)d_in[2];
  const int*   mask   = (const int*)d_in[3];
  const float* Wv = (const float*)d_in[4];
  const float* Wk = (const float*)d_in[5];
  const float* Wq = (const float*)d_in[6];
  const float* Wo = (const float*)d_in[7];
  const float* bo = (const float*)d_in[8];
  float* out = (float*)d_out;

  char* ws = (char*)d_ws;
  bf16_t*   Xbuf  = (bf16_t*)(ws);                 // 8192x2048 bf16 (33.5MB), reused for O
  bf16_t*   Wbuf  = (bf16_t*)(ws + 33554432);      // 2048x2048 bf16 (8.4MB)
  bf16_t*   Qb    = (bf16_t*)(ws + 41943040);      // [B][H][S][D]
  bf16_t*   Kb    = (bf16_t*)(ws + 75497472);      // [B][H][S][D]
  bf16_t*   Vtb   = (bf16_t*)(ws + 109051904);     // [B][H][D][S]
  uint32_t* maskb = (uint32_t*)(ws + 142606336);   // [S][64]

  dim3 b256(256);
  dim3 gconv(16384);     // 16.8M / 4 / 256
  dim3 gw(64, 64);
  dim3 gg(16, 64);       // N-tiles x M-tiles
  dim3 ga(16, 64);       // q-tiles x (B*H)

  pack_mask<<<dim3(512), b256, 0, stream>>>(mask, maskb);

  conv_bf16<<<gconv, b256, 0, stream>>>(query, Xbuf);
  convT_w<<<gw, b256, 0, stream>>>(Wq, Wbuf);
  gemm128<0><<<gg, b256, 0, stream>>>(Xbuf, Wbuf, Qb, nullptr, nullptr);

  conv_bf16<<<gconv, b256, 0, stream>>>(keys, Xbuf);
  convT_w<<<gw, b256, 0, stream>>>(Wk, Wbuf);
  gemm128<0><<<gg, b256, 0, stream>>>(Xbuf, Wbuf, Kb, nullptr, nullptr);

  conv_bf16<<<gconv, b256, 0, stream>>>(values, Xbuf);
  convT_w<<<gw, b256, 0, stream>>>(Wv, Wbuf);
  gemm128<1><<<gg, b256, 0, stream>>>(Xbuf, Wbuf, Vtb, nullptr, nullptr);

  attn_fwd<<<ga, b256, 0, stream>>>(Qb, Kb, Vtb, maskb, Xbuf);

  convT_w<<<gw, b256, 0, stream>>>(Wo, Wbuf);
  gemm128<2><<<gg, b256, 0, stream>>>(Xbuf, Wbuf, nullptr, out, bo);
}

// Round 3
// 674.945 us; speedup vs baseline: 1.0372x; 1.0372x over previous
//
#include <hip/hip_runtime.h>
#include <hip/hip_bf16.h>
#include <stdint.h>
#include <math.h>

#define EMB   2048
#define NH    16
#define HD    128
#define BATCH 4
#define SEQ   2048

typedef __bf16 bf16_t;
typedef __bf16 bf16x8 __attribute__((ext_vector_type(8)));
typedef __bf16 bf16x4 __attribute__((ext_vector_type(4)));
typedef float  f32x4  __attribute__((ext_vector_type(4)));
typedef float  f32x16 __attribute__((ext_vector_type(16)));

__device__ inline void gload_lds16(const void* g, void* l) {
  __builtin_amdgcn_global_load_lds(
      (const __attribute__((address_space(1))) uint32_t*)g,
      (__attribute__((address_space(3))) uint32_t*)l, 16, 0, 0);
}

__device__ inline uint32_t pack_bf2(float a, float b) {
  uint16_t lo = __builtin_bit_cast(uint16_t, (bf16_t)a);
  uint16_t hi = __builtin_bit_cast(uint16_t, (bf16_t)b);
  return (uint32_t)lo | ((uint32_t)hi << 16);
}

__device__ inline float ex2(float x) {
#if __has_builtin(__builtin_amdgcn_exp2f)
  return __builtin_amdgcn_exp2f(x);
#else
  float r; asm volatile("v_exp_f32 %0, %1" : "=v"(r) : "v"(x)); return r;
#endif
}

// ---------------- input conversion kernels ----------------

__global__ __launch_bounds__(256) void conv_bf16(const float* __restrict__ x,
                                                 bf16_t* __restrict__ y) {
  size_t t = (size_t)blockIdx.x * 256 + threadIdx.x;
  float4 v = ((const float4*)x)[t];
  bf16x4 o;
  o[0] = (bf16_t)v.x; o[1] = (bf16_t)v.y; o[2] = (bf16_t)v.z; o[3] = (bf16_t)v.w;
  ((bf16x4*)y)[t] = o;
}

// W[k][n] f32 -> Wt[n][k] bf16 (LDS 32x32 tile transpose)
__global__ __launch_bounds__(256) void convT_w(const float* __restrict__ W,
                                               bf16_t* __restrict__ Wt) {
  __shared__ float t[32][33];
  int tx = threadIdx.x & 31, ty = threadIdx.x >> 5;
  int nb = blockIdx.x * 32, kb = blockIdx.y * 32;
#pragma unroll
  for (int i = 0; i < 4; ++i)
    t[ty + 8 * i][tx] = W[(size_t)(kb + ty + 8 * i) * EMB + nb + tx];
  __syncthreads();
#pragma unroll
  for (int i = 0; i < 4; ++i)
    Wt[(size_t)(nb + ty + 8 * i) * EMB + kb + tx] = (bf16_t)t[tx][ty + 8 * i];
}

// mask int32 [S][S] -> bitmask [S][S/32]
__global__ __launch_bounds__(256) void pack_mask(const int* __restrict__ mask,
                                                 uint32_t* __restrict__ maskb) {
  int t = blockIdx.x * 256 + threadIdx.x;   // t < 2048*64
  int q = t >> 6, w = t & 63;
  const int* row = mask + (size_t)q * SEQ + w * 32;
  uint32_t acc = 0;
#pragma unroll 8
  for (int i = 0; i < 32; ++i) acc |= (row[i] != 0 ? 1u : 0u) << i;
  maskb[t] = acc;
}

// ---------------- 128x128 bf16 GEMM (m97 structure) ----------------
// C[M=8192][N=2048] = A[M][K=2048] * Wt[N][K]^T
// MODE 0: out bf16 [B][H][S][D]   (Q,K)
// MODE 1: out bf16 [B][H][D][S]   (V transposed; computes C^T via swapped
//         mfma operands so the lane-varying store index is s -> coalesced)
// MODE 2: out f32 [M][N] + bias[n]
template <int MODE>
__global__ __launch_bounds__(256) void gemm128(const bf16_t* __restrict__ A,
                                               const bf16_t* __restrict__ Bt,
                                               bf16_t* __restrict__ outb,
                                               float* __restrict__ outf,
                                               const float* __restrict__ bias) {
  __shared__ bf16_t As[128 * 32];
  __shared__ bf16_t Bs[128 * 32];
  const int tid = threadIdx.x;
  const int wid = tid >> 6, lane = tid & 63;
  const int wr = wid >> 1, wc = wid & 1;
  const int m0 = blockIdx.y * 128, n0 = blockIdx.x * 128;

  f32x4 acc[4][4] = {};

  const int sr = lane >> 2;          // row within 16-row staging group
  const int sc = (lane & 3) * 8;     // k element offset (16B chunk)
  const int ia0 = wid * 2;

  for (int kt = 0; kt < EMB / 32; ++kt) {
    const int k0 = kt * 32;
#pragma unroll
    for (int j = 0; j < 2; ++j) {
      int i = ia0 + j;
      int r = i * 16 + sr;
      gload_lds16(&A[(size_t)(m0 + r) * EMB + k0 + sc], &As[i * 512]);
      gload_lds16(&Bt[(size_t)(n0 + r) * EMB + k0 + sc], &Bs[i * 512]);
    }
    asm volatile("s_waitcnt vmcnt(0)" ::: "memory");
    __syncthreads();

    const int fr = lane & 15;
    const int fk = (lane >> 4) * 8;
    bf16x8 af[4], bfr[4];
#pragma unroll
    for (int mf = 0; mf < 4; ++mf)
      af[mf] = *(const bf16x8*)&As[(wr * 64 + mf * 16 + fr) * 32 + fk];
#pragma unroll
    for (int nf = 0; nf < 4; ++nf)
      bfr[nf] = *(const bf16x8*)&Bs[(wc * 64 + nf * 16 + fr) * 32 + fk];
#pragma unroll
    for (int mf = 0; mf < 4; ++mf)
#pragma unroll
      for (int nf = 0; nf < 4; ++nf) {
        if (MODE == 1)
          acc[mf][nf] = __builtin_amdgcn_mfma_f32_16x16x32_bf16(bfr[nf], af[mf],
                                                                acc[mf][nf], 0, 0, 0);
        else
          acc[mf][nf] = __builtin_amdgcn_mfma_f32_16x16x32_bf16(af[mf], bfr[nf],
                                                                acc[mf][nf], 0, 0, 0);
      }
    __syncthreads();
  }

  // epilogue.  D layout (16x16): col = lane&15, row = (lane>>4)*4 + r
  const int col0 = lane & 15;
  const int row0 = (lane >> 4) * 4;
#pragma unroll
  for (int mf = 0; mf < 4; ++mf) {
#pragma unroll
    for (int r = 0; r < 4; ++r) {
#pragma unroll
      for (int nf = 0; nf < 4; ++nf) {
        float v = acc[mf][nf][r];
        if (MODE == 1) {
          // D = C^T : fragment rows are the n (d) dim, cols are the m (s) dim
          int nr = n0 + wc * 64 + nf * 16 + row0 + r;
          int mc = m0 + wr * 64 + mf * 16 + col0;
          int b = mc >> 11, s = mc & 2047, h = nr >> 7, d = nr & 127;
          outb[((size_t)(b * NH + h) * HD + d) * SEQ + s] = (bf16_t)v;
        } else {
          int m = m0 + wr * 64 + mf * 16 + row0 + r;
          int n = n0 + wc * 64 + nf * 16 + col0;
          if (MODE == 0) {
            int b = m >> 11, s = m & 2047, h = n >> 7, d = n & 127;
            outb[((size_t)(b * NH + h) * SEQ + s) * HD + d] = (bf16_t)v;
          } else {
            outf[(size_t)m * EMB + n] = v + bias[n];
          }
        }
      }
    }
  }
}

// ---------------- fused masked flash attention ----------------
// Q,K: [B][H][S][D] bf16; Vt: [B][H][D][S] bf16; O: [B][S][E] bf16 (merged heads)
// 4 waves/block, 32 q-rows/wave, KV tile = 64, double-buffered LDS with
// counted vmcnt (T3/T4) + setprio (T5) + exp2-folded deferred softmax (T13).
// Swapped-operand MFMA: S^T = mfma(K,Q), O^T = mfma(Vt,P^T); lane l and l^32
// share q, each holds half the s_local values -> pair-reduce max/sum via ^32.
__global__ __launch_bounds__(256, 2) void attn_fwd(const bf16_t* __restrict__ Q,
                                                   const bf16_t* __restrict__ K,
                                                   const bf16_t* __restrict__ Vt,
                                                   const uint32_t* __restrict__ maskb,
                                                   bf16_t* __restrict__ O) {
  __shared__ bf16_t Ks[2][64 * 128];   // [s][d], 16B-chunk XOR swizzle by (s&7)
  __shared__ bf16_t Vs[2][128 * 64];   // [d][j], 16B-chunk XOR swizzle by (d&7)
  const int tid = threadIdx.x;
  const int wid = tid >> 6, lane = tid & 63;
  const int ln = lane & 31, hi = lane >> 5;
  // XCD-aware decode: all 16 q-tiles of one head land on one XCD (L2 sharing)
  const int bid = blockIdx.x;
  const int slot = bid >> 3;
  const int bh = (bid & 7) * 8 + (slot >> 4);
  const int qt = slot & 15;
  const int b = bh >> 4, h = bh & 15;
  const int q = qt * 128 + wid * 32 + ln;           // this lane's query row
  const float C2 = 0.08838834764831845f * 1.4426950408889634f;  // scale*log2e

  // Q fragments in registers (B-operand of swapped QK^T)
  bf16x8 qf[8];
  const bf16_t* qrow = Q + ((size_t)bh * SEQ + q) * HD;
#pragma unroll
  for (int ks = 0; ks < 8; ++ks)
    qf[ks] = *(const bf16x8*)&qrow[ks * 16 + hi * 8];

  f32x16 oacc[4] = {};
  float mC = -INFINITY, l_run = 0.f;

  const size_t kbase = (size_t)bh * SEQ * HD;
  const size_t vbase = (size_t)bh * HD * SEQ;

#define STAGE(BUF, KT)                                                          \
  do {                                                                          \
    const int _k0 = (KT) * 64;                                                  \
    _Pragma("unroll")                                                           \
    for (int j = 0; j < 4; ++j) {                                               \
      int i = wid * 4 + j;                                                      \
      { int r = i * 4 + (lane >> 4); int c = lane & 15;                         \
        gload_lds16(&K[kbase + (size_t)(_k0 + r) * HD + ((c ^ (r & 7)) * 8)],   \
                    &Ks[BUF][i * 512]); }                                       \
      { int r = i * 8 + (lane >> 3); int c = lane & 7;                          \
        gload_lds16(&Vt[vbase + (size_t)r * SEQ + _k0 + ((c ^ (r & 7)) * 8)],   \
                    &Vs[BUF][i * 512]); }                                       \
    }                                                                           \
  } while (0)

  STAGE(0, 0);
  const int NT = SEQ / 64;
  for (int kt = 0; kt < NT; ++kt) {
    const int cur = kt & 1;
    if (kt + 1 < NT) {
      STAGE(cur ^ 1, kt + 1);                         // issue next tile's DMA
      asm volatile("s_waitcnt vmcnt(8)" ::: "memory"); // current tile done
    } else {
      asm volatile("s_waitcnt vmcnt(0)" ::: "memory");
    }
    asm volatile("s_barrier" ::: "memory");           // raw: no vmcnt(0) drain

    const bf16_t* KsC = Ks[cur];
    const bf16_t* VsC = Vs[cur];

    // S^T[s_local][q] : 64 x 32 per wave, 2 M-frags
    f32x16 sacc[2] = {};
    __builtin_amdgcn_s_setprio(1);
#pragma unroll
    for (int ks = 0; ks < 8; ++ks) {
#pragma unroll
      for (int mf = 0; mf < 2; ++mf) {
        int row = mf * 32 + ln;
        bf16x8 kf = *(const bf16x8*)&KsC[row * 128 + (((2 * ks + hi) ^ (row & 7)) * 8)];
        sacc[mf] = __builtin_amdgcn_mfma_f32_32x32x16_bf16(kf, qf[ks], sacc[mf], 0, 0, 0);
      }
    }
    __builtin_amdgcn_s_setprio(0);

    // mask + online softmax (exp2-domain, deferred rescale)
    const uint2 mw = *(const uint2*)&maskb[(size_t)q * 64 + (kt * 2)];
    float v0[16], v1[16];
    float pmax = -INFINITY;
#pragma unroll
    for (int r = 0; r < 16; ++r) {
      const int bit = (r & 3) + 8 * (r >> 2) + 4 * hi;   // s_local within 32-block
      float va = ((mw.x >> bit) & 1) ? sacc[0][r] : -INFINITY;
      float vb = ((mw.y >> bit) & 1) ? sacc[1][r] : -INFINITY;
      v0[r] = va; v1[r] = vb;
      pmax = fmaxf(pmax, fmaxf(va, vb));
    }
    pmax = fmaxf(pmax, __shfl_xor(pmax, 32, 64));        // pair-reduce max
    const float pmaxC = pmax * C2;
    if (!__all(pmaxC - mC <= 8.0f)) {                    // T13 defer-rescale
      const float mnewC = fmaxf(mC, pmaxC);
      const float corr = ex2(mC - mnewC);
#pragma unroll
      for (int mv = 0; mv < 4; ++mv)
#pragma unroll
        for (int r = 0; r < 16; ++r) oacc[mv][r] *= corr;
      l_run *= corr;
      mC = mnewC;
    }
    float psum = 0.f;
    uint32_t pk[2][4][2];
#pragma unroll
    for (int g = 0; g < 4; ++g) {
      float p0 = ex2(fmaf(v0[4 * g + 0], C2, -mC));
      float p1 = ex2(fmaf(v0[4 * g + 1], C2, -mC));
      float p2 = ex2(fmaf(v0[4 * g + 2], C2, -mC));
      float p3 = ex2(fmaf(v0[4 * g + 3], C2, -mC));
      psum += (p0 + p1) + (p2 + p3);
      pk[0][g][0] = pack_bf2(p0, p1);
      pk[0][g][1] = pack_bf2(p2, p3);
      float q0 = ex2(fmaf(v1[4 * g + 0], C2, -mC));
      float q1 = ex2(fmaf(v1[4 * g + 1], C2, -mC));
      float q2 = ex2(fmaf(v1[4 * g + 2], C2, -mC));
      float q3 = ex2(fmaf(v1[4 * g + 3], C2, -mC));
      psum += (q0 + q1) + (q2 + q3);
      pk[1][g][0] = pack_bf2(q0, q1);
      pk[1][g][1] = pack_bf2(q2, q3);
    }
    psum += __shfl_xor(psum, 32, 64);                    // pair-reduce sum
    l_run += psum;

    // O^T[d][q] += Vt[d][j] * P^T[j][q].  Partner exchange: send exactly the
    // word the partner needs (hi=1 sends gA for its hi=0 partner, and vice
    // versa) -> 2 shuffles per ks instead of 4.
#pragma unroll
    for (int ks = 0; ks < 4; ++ks) {
      const int mfp = ks >> 1;
      const int gA = (2 * ks) & 3;
      const int gB = (2 * ks + 1) & 3;
      uint32_t s0w = hi ? pk[mfp][gA][0] : pk[mfp][gB][0];
      uint32_t s1w = hi ? pk[mfp][gA][1] : pk[mfp][gB][1];
      uint32_t r0 = (uint32_t)__shfl_xor((int)s0w, 32, 64);
      uint32_t r1 = (uint32_t)__shfl_xor((int)s1w, 32, 64);
      uint32_t b0 = hi ? r0 : pk[mfp][gA][0];
      uint32_t b1 = hi ? r1 : pk[mfp][gA][1];
      uint32_t b2 = hi ? pk[mfp][gB][0] : r0;
      uint32_t b3 = hi ? pk[mfp][gB][1] : r1;
      uint4 bw = make_uint4(b0, b1, b2, b3);
      bf16x8 pb = __builtin_bit_cast(bf16x8, bw);
      __builtin_amdgcn_s_setprio(1);
#pragma unroll
      for (int mv = 0; mv < 4; ++mv) {
        int row = mv * 32 + ln;
        bf16x8 vf = *(const bf16x8*)&VsC[row * 64 + (((2 * ks + hi) ^ (row & 7)) * 8)];
        oacc[mv] = __builtin_amdgcn_mfma_f32_32x32x16_bf16(vf, pb, oacc[mv], 0, 0, 0);
      }
      __builtin_amdgcn_s_setprio(0);
    }
    asm volatile("s_barrier" ::: "memory");   // all reads of buf[cur] done
  }
#undef STAGE

  // epilogue: O[b][q][h*128+d] = oacc/l ; D rows d = (r&3)+8*(r>>2)+4*hi (+32*mv)
  const float invl = 1.f / l_run;
  bf16_t* orow = O + ((size_t)b * SEQ + q) * EMB + h * HD;
#pragma unroll
  for (int mv = 0; mv < 4; ++mv) {
#pragma unroll
    for (int g = 0; g < 4; ++g) {
      int d = mv * 32 + 8 * g + 4 * hi;
      bf16x4 ov;
      ov[0] = (bf16_t)(oacc[mv][4 * g + 0] * invl);
      ov[1] = (bf16_t)(oacc[mv][4 * g + 1] * invl);
      ov[2] = (bf16_t)(oacc[mv][4 * g + 2] * invl);
      ov[3] = (bf16_t)(oacc[mv][4 * g + 3] * invl);
      *(bf16x4*)&orow[d] = ov;
    }
  }
}

// ---------------- host launch ----------------

extern "C" void kernel_launch(void* const* d_in, const int* in_sizes, int n_in,
                              void* d_out, int out_size, void* d_ws, size_t ws_size,
                              hipStream_t stream) {
  const float* values = (const float*)d_in[0];
  const float* keys   = (const float*)d_in[1];
  const float* query  = (const float*)d_in[2];
  const int*   mask   = (const int*)d_in[3];
  const float* Wv = (const float*)d_in[4];
  const float* Wk = (const float*)d_in[5];
  const float* Wq = (const float*)d_in[6];
  const float* Wo = (const float*)d_in[7];
  const float* bo = (const float*)d_in[8];
  float* out = (float*)d_out;

  char* ws = (char*)d_ws;
  bf16_t*   Xbuf  = (bf16_t*)(ws);                 // 8192x2048 bf16 (33.5MB), reused for O
  bf16_t*   Wbuf  = (bf16_t*)(ws + 33554432);      // 2048x2048 bf16 (8.4MB)
  bf16_t*   Qb    = (bf16_t*)(ws + 41943040);      // [B][H][S][D]
  bf16_t*   Kb    = (bf16_t*)(ws + 75497472);      // [B][H][S][D]
  bf16_t*   Vtb   = (bf16_t*)(ws + 109051904);     // [B][H][D][S]
  uint32_t* maskb = (uint32_t*)(ws + 142606336);   // [S][64]

  dim3 b256(256);
  dim3 gconv(16384);     // 16.8M / 4 / 256
  dim3 gw(64, 64);
  dim3 gg(16, 64);       // N-tiles x M-tiles
  dim3 ga(1024);         // XCD-swizzled 1D grid: 16 q-tiles x 64 bh

  pack_mask<<<dim3(512), b256, 0, stream>>>(mask, maskb);

  conv_bf16<<<gconv, b256, 0, stream>>>(query, Xbuf);
  convT_w<<<gw, b256, 0, stream>>>(Wq, Wbuf);
  gemm128<0><<<gg, b256, 0, stream>>>(Xbuf, Wbuf, Qb, nullptr, nullptr);

  conv_bf16<<<gconv, b256, 0, stream>>>(keys, Xbuf);
  convT_w<<<gw, b256, 0, stream>>>(Wk, Wbuf);
  gemm128<0><<<gg, b256, 0, stream>>>(Xbuf, Wbuf, Kb, nullptr, nullptr);

  conv_bf16<<<gconv, b256, 0, stream>>>(values, Xbuf);
  convT_w<<<gw, b256, 0, stream>>>(Wv, Wbuf);
  gemm128<1><<<gg, b256, 0, stream>>>(Xbuf, Wbuf, Vtb, nullptr, nullptr);

  attn_fwd<<<ga, b256, 0, stream>>>(Qb, Kb, Vtb, maskb, Xbuf);

  convT_w<<<gw, b256, 0, stream>>>(Wo, Wbuf);
  gemm128<2><<<gg, b256, 0, stream>>>(Xbuf, Wbuf, nullptr, out, bo);
}